// Round 11
// baseline (264.688 us; speedup 1.0000x reference)
//
#include <hip/hip_runtime.h>
#include <float.h>

// AttentionAgg via destination-CSR (no float atomics).
//   score = M @ a; smax = segmax(score,dest); ex = exp(score-smax[dest])
//   denom = segsum(ex,dest); alpha = ex/denom[dest]
//   Mv = segsum(alpha*M, dest); out = Mv[src] - alpha[rev]*M[rev]
//
// E = 800000, d = 64, N = 50000 (dim_size is a device scalar; hardcoded).
//
// Round-9 -> 10 deltas (theory: gather kernels are latency-bound with one
// dependent chain per 16-lane group; VGPR=8 shows huge register headroom):
//  (1) k_out: 4 edges per group via grid-stride register blocking -- all
//      index loads issue, then alpha loads, then 8 row gathers in flight,
//      then 4 nontemporal stores. 4 independent chains per thread.
//  (2) k_score_fill: 2 edges per group, interleaved dot + shfl-reduce chains.
//  (3) k_aggregate unchanged (isolate the ILP variable).
// (Round-10/11: resubmission; bench infra failed, kernel never ran.)

#define THREADS 256

typedef float f32x4 __attribute__((ext_vector_type(4)));

// ---------------------------------------------------------------------------
// K0: zero counts[N] + total counter (N+4 ints, multiple of 4).
__global__ void k_zero(int4* __restrict__ p, int n4) {
    int i = blockIdx.x * blockDim.x + threadIdx.x;
    if (i < n4) p[i] = make_int4(0, 0, 0, 0);
}

// ---------------------------------------------------------------------------
// K1: histogram of dest (reads 3.2MB only).
__global__ void k_hist(const int* __restrict__ dest,
                       int* __restrict__ counts, int E) {
    int e = blockIdx.x * blockDim.x + threadIdx.x;
    if (e >= E) return;
    atomicAdd(&counts[dest[e]], 1);
}

// ---------------------------------------------------------------------------
// K2: range allocation. Wave-level exclusive prefix over counts + one
// atomicAdd(total) per wave -> offsets[n], cursor[n].
__global__ void k_alloc(const int* __restrict__ counts,
                        int* __restrict__ total,
                        int* __restrict__ offsets,
                        int* __restrict__ cursor,
                        int N) {
    int n    = blockIdx.x * blockDim.x + threadIdx.x;
    int lane = threadIdx.x & 63;
    int c = (n < N) ? counts[n] : 0;
    int x = c;
    #pragma unroll
    for (int off = 1; off < 64; off <<= 1) {
        int y = __shfl_up(x, off, 64);
        if (lane >= off) x += y;
    }
    int wsum = __shfl(x, 63, 64);
    int base = 0;
    if (lane == 63) base = atomicAdd(total, wsum);
    base = __shfl(base, 63, 64);
    if (n < N) {
        int my = base + x - c;                 // exclusive position
        offsets[n] = my;
        cursor[n]  = my;
    }
}

// ---------------------------------------------------------------------------
// K3: fused score + bucket fill, ILP=2. Each 16-lane group handles edges
// g and g+nG (grid-strided): two independent float4-dot + 4-step shfl
// reduce chains interleaved; lane0 allocates CSR slots and writes
// sorted_eid / sorted_score for both.
__global__ void k_score_fill(const float4* __restrict__ M4,
                             const float4* __restrict__ a4,
                             const int* __restrict__ dest,
                             int* __restrict__ cursor,
                             int* __restrict__ sorted_eid,
                             float* __restrict__ sorted_score,
                             int E, int nG) {
    long long gid = (long long)blockIdx.x * blockDim.x + threadIdx.x;
    int g  = (int)(gid >> 4);
    int sl = (int)(gid & 15);
    if (g >= nG) return;
    int e0 = g;
    int e1 = g + nG;
    bool v1 = e1 < E;
    float4 av = a4[sl];                        // 256B, L1-resident
    float4 m0 = M4[(size_t)e0 * 16 + sl];
    float4 m1 = v1 ? M4[(size_t)e1 * 16 + sl] : m0;
    float s0 = m0.x * av.x + m0.y * av.y + m0.z * av.z + m0.w * av.w;
    float s1 = m1.x * av.x + m1.y * av.y + m1.z * av.z + m1.w * av.w;
    s0 += __shfl_xor(s0, 1, 64);  s1 += __shfl_xor(s1, 1, 64);
    s0 += __shfl_xor(s0, 2, 64);  s1 += __shfl_xor(s1, 2, 64);
    s0 += __shfl_xor(s0, 4, 64);  s1 += __shfl_xor(s1, 4, 64);
    s0 += __shfl_xor(s0, 8, 64);  s1 += __shfl_xor(s1, 8, 64);
    if (sl == 0) {
        int p0 = atomicAdd(&cursor[dest[e0]], 1);
        sorted_eid[p0]   = e0;
        sorted_score[p0] = s0;
        if (v1) {
            int p1 = atomicAdd(&cursor[dest[e1]], 1);
            sorted_eid[p1]   = e1;
            sorted_score[p1] = s1;
        }
    }
}

// ---------------------------------------------------------------------------
// K4: one wave per node; writes Mv row AND per-edge alpha.
// Fast path (deg<=64): lane loads (eid, score) COALESCED from the sorted
// arrays; wave-reduce max and exp-sum in registers; weighted pass uses a
// WAVE-UNIFORM trip count so every __shfl executes with all lanes active
// (round-5 lesson). Fallback (deg>64): two-pass, also on sorted arrays.
__global__ void k_aggregate(const float4* __restrict__ M4,
                            const float* __restrict__ sorted_score,
                            const int* __restrict__ sorted_eid,
                            const int* __restrict__ offsets,
                            const int* __restrict__ counts,
                            float4* __restrict__ Mv4,
                            float* __restrict__ alpha,
                            int N) {
    long long gid = (long long)blockIdx.x * blockDim.x + threadIdx.x;
    int n    = (int)(gid >> 6);
    int lane = (int)(gid & 63);
    if (n >= N) return;
    int beg = offsets[n];
    int deg = counts[n];
    int end = beg + deg;
    int grp = lane >> 4;
    int sl  = lane & 15;

    float4 acc = make_float4(0.f, 0.f, 0.f, 0.f);

    if (deg <= 64) {
        int   eid = 0;
        float sc  = -FLT_MAX;
        if (lane < deg) {
            eid = sorted_eid[beg + lane];      // coalesced
            sc  = sorted_score[beg + lane];    // coalesced
        }
        float m = sc;
        #pragma unroll
        for (int off = 32; off; off >>= 1)
            m = fmaxf(m, __shfl_xor(m, off, 64));
        float exr = (lane < deg) ? expf(sc - m) : 0.f;
        float ds  = exr;
        #pragma unroll
        for (int off = 32; off; off >>= 1)
            ds += __shfl_xor(ds, off, 64);
        float inv = ds > 0.f ? 1.0f / ds : 0.0f;
        if (lane < deg) alpha[eid] = exr * inv;     // fused k_alpha
        // wave-uniform trip count; shfl src lane i = grp+4k <= 63, active.
        int iters = (deg + 3) >> 2;
        for (int k = 0; k < iters; ++k) {
            int i = grp + 4 * k;
            float ex = __shfl(exr, i, 64);
            int   e  = __shfl(eid, i, 64);
            if (i < deg) {
                float4 mm = M4[(size_t)e * 16 + sl];
                acc.x += ex * mm.x;
                acc.y += ex * mm.y;
                acc.z += ex * mm.z;
                acc.w += ex * mm.w;
            }
        }
        acc.x += __shfl_xor(acc.x, 16, 64);  acc.x += __shfl_xor(acc.x, 32, 64);
        acc.y += __shfl_xor(acc.y, 16, 64);  acc.y += __shfl_xor(acc.y, 32, 64);
        acc.z += __shfl_xor(acc.z, 16, 64);  acc.z += __shfl_xor(acc.z, 32, 64);
        acc.w += __shfl_xor(acc.w, 16, 64);  acc.w += __shfl_xor(acc.w, 32, 64);
        if (lane < 16) {
            float4 o;
            o.x = acc.x * inv; o.y = acc.y * inv;
            o.z = acc.z * inv; o.w = acc.w * inv;
            Mv4[(size_t)n * 16 + lane] = o;
        }
    } else {
        float m = -FLT_MAX;
        for (int i = beg + lane; i < end; i += 64)
            m = fmaxf(m, sorted_score[i]);
        #pragma unroll
        for (int off = 32; off; off >>= 1)
            m = fmaxf(m, __shfl_xor(m, off, 64));
        float dsum = 0.f;
        for (int i = beg + grp; i < end; i += 4) {
            int e = sorted_eid[i];
            float ex = expf(sorted_score[i] - m);
            if (sl == 0) dsum += ex;
            float4 mm = M4[(size_t)e * 16 + sl];
            acc.x += ex * mm.x;
            acc.y += ex * mm.y;
            acc.z += ex * mm.z;
            acc.w += ex * mm.w;
        }
        dsum += __shfl_xor(dsum, 16, 64);
        dsum += __shfl_xor(dsum, 32, 64);
        float dtot = __shfl(dsum, 0, 64);
        float inv = dtot > 0.f ? 1.0f / dtot : 0.0f;
        for (int i = beg + lane; i < end; i += 64) {
            alpha[sorted_eid[i]] = expf(sorted_score[i] - m) * inv;
        }
        acc.x += __shfl_xor(acc.x, 16, 64);  acc.x += __shfl_xor(acc.x, 32, 64);
        acc.y += __shfl_xor(acc.y, 16, 64);  acc.y += __shfl_xor(acc.y, 32, 64);
        acc.z += __shfl_xor(acc.z, 16, 64);  acc.z += __shfl_xor(acc.z, 32, 64);
        acc.w += __shfl_xor(acc.w, 16, 64);  acc.w += __shfl_xor(acc.w, 32, 64);
        if (lane < 16) {
            float4 o;
            o.x = acc.x * inv; o.y = acc.y * inv;
            o.z = acc.z * inv; o.w = acc.w * inv;
            Mv4[(size_t)n * 16 + lane] = o;
        }
    }
}

// ---------------------------------------------------------------------------
// K5: out = Mv[src] - alpha[rev] * M[rev], ILP=4. Each 16-lane group handles
// edges g+k*nG (k=0..3): 4 independent index->alpha->gather->store chains so
// the memory system has 8 row gathers in flight per group. Nontemporal store
// keeps the 205MB out-stream from evicting M in L3.
__global__ void k_out(const float4* __restrict__ M4,
                      const float4* __restrict__ Mv4,
                      const float* __restrict__ alpha,
                      const int* __restrict__ src,
                      const int* __restrict__ rev,
                      f32x4* __restrict__ out4,
                      int E, int nG) {
    long long gid = (long long)blockIdx.x * blockDim.x + threadIdx.x;
    int g  = (int)(gid >> 4);
    int sl = (int)(gid & 15);
    if (g >= nG) return;
    int  e[4];
    bool v[4];
    #pragma unroll
    for (int k = 0; k < 4; ++k) { e[k] = g + k * nG; v[k] = e[k] < E; }
    int s[4], r[4];
    #pragma unroll
    for (int k = 0; k < 4; ++k) {
        s[k] = v[k] ? src[e[k]] : 0;
        r[k] = v[k] ? rev[e[k]] : 0;
    }
    float al[4];
    #pragma unroll
    for (int k = 0; k < 4; ++k) al[k] = v[k] ? alpha[r[k]] : 0.f;
    float4 mv[4], mr[4];
    #pragma unroll
    for (int k = 0; k < 4; ++k) {
        if (v[k]) {
            mv[k] = Mv4[(size_t)s[k] * 16 + sl];
            mr[k] = M4[(size_t)r[k] * 16 + sl];
        }
    }
    #pragma unroll
    for (int k = 0; k < 4; ++k) {
        if (v[k]) {
            f32x4 o;
            o.x = mv[k].x - al[k] * mr[k].x;
            o.y = mv[k].y - al[k] * mr[k].y;
            o.z = mv[k].z - al[k] * mr[k].z;
            o.w = mv[k].w - al[k] * mr[k].w;
            __builtin_nontemporal_store(o, &out4[(size_t)e[k] * 16 + sl]);
        }
    }
}

// ---------------------------------------------------------------------------
extern "C" void kernel_launch(void* const* d_in, const int* in_sizes, int n_in,
                              void* d_out, int out_size, void* d_ws, size_t ws_size,
                              hipStream_t stream) {
    const float* M  = (const float*)d_in[0];
    const float* a  = (const float*)d_in[1];
    const int* eidx = (const int*)d_in[2];   // [2, E] flat: src row, dest row
    const int* rev  = (const int*)d_in[3];
    const int N = 50000;
    const int E = in_sizes[3];

    const int* src  = eidx;
    const int* dest = eidx + E;

    // Workspace: Mv[N*64] | sorted_score[E] | alpha[E] | sorted_eid[E] |
    //            counts[N]+total[4] | offsets[N] | cursor[N]
    char* ws = (char*)d_ws;
    float* Mv          = (float*)ws; ws += (size_t)N * 64 * 4;
    float* sorted_score= (float*)ws; ws += (size_t)E * 4;
    float* alpha       = (float*)ws; ws += (size_t)E * 4;
    int*   sorted_eid  = (int*)ws;   ws += (size_t)E * 4;
    int*   counts      = (int*)ws;   ws += (size_t)(N + 4) * 4;  // +total
    int*   offsets     = (int*)ws;   ws += (size_t)N * 4;
    int*   cursor      = (int*)ws;   ws += (size_t)N * 4;
    int*   total       = counts + N;

    int blocksE   = (E + THREADS - 1) / THREADS;
    int blocksN   = (N + THREADS - 1) / THREADS;
    int blocksN64 = (int)(((long long)N * 64 + THREADS - 1) / THREADS);
    int n4        = (N + 4) / 4;               // counts + total
    int blocksZ   = (n4 + THREADS - 1) / THREADS;

    int nG2 = (E + 1) / 2;                     // score_fill groups (ILP=2)
    int blocksSF = (int)(((long long)nG2 * 16 + THREADS - 1) / THREADS);
    int nG4 = (E + 3) / 4;                     // out groups (ILP=4)
    int blocksOut = (int)(((long long)nG4 * 16 + THREADS - 1) / THREADS);

    k_zero<<<blocksZ, THREADS, 0, stream>>>((int4*)counts, n4);
    k_hist<<<blocksE, THREADS, 0, stream>>>(dest, counts, E);
    k_alloc<<<blocksN, THREADS, 0, stream>>>(counts, total, offsets, cursor, N);
    k_score_fill<<<blocksSF, THREADS, 0, stream>>>(
        (const float4*)M, (const float4*)a, dest, cursor,
        sorted_eid, sorted_score, E, nG2);
    k_aggregate<<<blocksN64, THREADS, 0, stream>>>(
        (const float4*)M, sorted_score, sorted_eid, offsets, counts,
        (float4*)Mv, alpha, N);
    k_out<<<blocksOut, THREADS, 0, stream>>>(
        (const float4*)M, (const float4*)Mv, alpha, src, rev,
        (f32x4*)d_out, E, nG4);
}

// Round 12
// 260.876 us; speedup vs baseline: 1.0146x; 1.0146x over previous
//
#include <hip/hip_runtime.h>
#include <float.h>

// AttentionAgg via destination-CSR (no float atomics).
//   score = M @ a; smax = segmax(score,dest); ex = exp(score-smax[dest])
//   denom = segsum(ex,dest); alpha = ex/denom[dest]
//   Mv = segsum(alpha*M, dest); out = Mv[src] - alpha[rev]*M[rev]
//
// E = 800000, d = 64, N = 50000 (dim_size is a device scalar; hardcoded).
//
// Round-11 -> 12 delta: ILP experiment was neutral (gathers are
// throughput-bound, not latency-bound) -> reverted. New lever: bf16 shadow
// copy of M written during the streaming score pass; both gather kernels
// (k_aggregate, k_out) read 8B/lane bf16 rows instead of 16B/lane f32,
// halving the 410MB random-gather traffic for +102MB of streaming write.
// All accumulation stays f32; score uses f32 M (exp path untouched).
// f32 fallback if ws_size can't hold the shadow copy.

#define THREADS 256

typedef float f32x4 __attribute__((ext_vector_type(4)));

__device__ __forceinline__ unsigned short bf16_rn(float x) {
    unsigned u = __float_as_uint(x);
    u += 0x7FFFu + ((u >> 16) & 1u);      // round-to-nearest-even
    return (unsigned short)(u >> 16);
}
__device__ __forceinline__ float bf16_f(unsigned short h) {
    return __uint_as_float(((unsigned)h) << 16);
}

// ---------------------------------------------------------------------------
// K0: zero counts[N] + total counter (N+4 ints, multiple of 4).
__global__ void k_zero(int4* __restrict__ p, int n4) {
    int i = blockIdx.x * blockDim.x + threadIdx.x;
    if (i < n4) p[i] = make_int4(0, 0, 0, 0);
}

// ---------------------------------------------------------------------------
// K1: histogram of dest (reads 3.2MB only).
__global__ void k_hist(const int* __restrict__ dest,
                       int* __restrict__ counts, int E) {
    int e = blockIdx.x * blockDim.x + threadIdx.x;
    if (e >= E) return;
    atomicAdd(&counts[dest[e]], 1);
}

// ---------------------------------------------------------------------------
// K2: range allocation. Wave-level exclusive prefix over counts + one
// atomicAdd(total) per wave -> offsets[n], cursor[n].
__global__ void k_alloc(const int* __restrict__ counts,
                        int* __restrict__ total,
                        int* __restrict__ offsets,
                        int* __restrict__ cursor,
                        int N) {
    int n    = blockIdx.x * blockDim.x + threadIdx.x;
    int lane = threadIdx.x & 63;
    int c = (n < N) ? counts[n] : 0;
    int x = c;
    #pragma unroll
    for (int off = 1; off < 64; off <<= 1) {
        int y = __shfl_up(x, off, 64);
        if (lane >= off) x += y;
    }
    int wsum = __shfl(x, 63, 64);
    int base = 0;
    if (lane == 63) base = atomicAdd(total, wsum);
    base = __shfl(base, 63, 64);
    if (n < N) {
        int my = base + x - c;                 // exclusive position
        offsets[n] = my;
        cursor[n]  = my;
    }
}

// ---------------------------------------------------------------------------
// K3: fused score + bucket fill (+ bf16 shadow write of M when BF).
// 16 lanes/edge, float4 loads; lane0 allocates the CSR slot.
template<bool BF>
__global__ void k_score_fill(const float4* __restrict__ M4,
                             const float4* __restrict__ a4,
                             const int* __restrict__ dest,
                             int* __restrict__ cursor,
                             int* __restrict__ sorted_eid,
                             float* __restrict__ sorted_score,
                             ushort4* __restrict__ Mbf,
                             int E) {
    long long gid = (long long)blockIdx.x * blockDim.x + threadIdx.x;
    int e  = (int)(gid >> 4);
    int sl = (int)(gid & 15);
    if (e >= E) return;
    float4 m  = M4[(size_t)e * 16 + sl];
    if (BF) {
        ushort4 h;
        h.x = bf16_rn(m.x); h.y = bf16_rn(m.y);
        h.z = bf16_rn(m.z); h.w = bf16_rn(m.w);
        Mbf[(size_t)e * 16 + sl] = h;          // streaming 128B/row
    }
    float4 av = a4[sl];                        // 256B, L1-resident
    float v = m.x * av.x + m.y * av.y + m.z * av.z + m.w * av.w;
    v += __shfl_xor(v, 1, 64);
    v += __shfl_xor(v, 2, 64);
    v += __shfl_xor(v, 4, 64);
    v += __shfl_xor(v, 8, 64);
    if (sl == 0) {
        int pos = atomicAdd(&cursor[dest[e]], 1);
        sorted_eid[pos]   = e;
        sorted_score[pos] = v;
    }
}

// ---------------------------------------------------------------------------
// Row load helper: 4 consecutive elements (lane slice sl) of row e.
template<bool BF>
__device__ __forceinline__ float4 load_row(const float4* M4,
                                           const ushort4* Mbf,
                                           int e, int sl) {
    if (BF) {
        ushort4 h = Mbf[(size_t)e * 16 + sl];  // 8B gather
        float4 r;
        r.x = bf16_f(h.x); r.y = bf16_f(h.y);
        r.z = bf16_f(h.z); r.w = bf16_f(h.w);
        return r;
    }
    return M4[(size_t)e * 16 + sl];            // 16B gather
}

// ---------------------------------------------------------------------------
// K4: one wave per node; writes Mv row AND per-edge alpha.
// Fast path (deg<=64): lane loads (eid, score) COALESCED; wave-reduce max
// and exp-sum in registers; weighted pass uses a WAVE-UNIFORM trip count so
// every __shfl executes with all lanes active (round-5 lesson).
// Fallback (deg>64): two-pass on sorted arrays.
template<bool BF>
__global__ void k_aggregate(const float4* __restrict__ M4,
                            const ushort4* __restrict__ Mbf,
                            const float* __restrict__ sorted_score,
                            const int* __restrict__ sorted_eid,
                            const int* __restrict__ offsets,
                            const int* __restrict__ counts,
                            float4* __restrict__ Mv4,
                            float* __restrict__ alpha,
                            int N) {
    long long gid = (long long)blockIdx.x * blockDim.x + threadIdx.x;
    int n    = (int)(gid >> 6);
    int lane = (int)(gid & 63);
    if (n >= N) return;
    int beg = offsets[n];
    int deg = counts[n];
    int end = beg + deg;
    int grp = lane >> 4;
    int sl  = lane & 15;

    float4 acc = make_float4(0.f, 0.f, 0.f, 0.f);

    if (deg <= 64) {
        int   eid = 0;
        float sc  = -FLT_MAX;
        if (lane < deg) {
            eid = sorted_eid[beg + lane];      // coalesced
            sc  = sorted_score[beg + lane];    // coalesced
        }
        float m = sc;
        #pragma unroll
        for (int off = 32; off; off >>= 1)
            m = fmaxf(m, __shfl_xor(m, off, 64));
        float exr = (lane < deg) ? expf(sc - m) : 0.f;
        float ds  = exr;
        #pragma unroll
        for (int off = 32; off; off >>= 1)
            ds += __shfl_xor(ds, off, 64);
        float inv = ds > 0.f ? 1.0f / ds : 0.0f;
        if (lane < deg) alpha[eid] = exr * inv;     // fused k_alpha
        // wave-uniform trip count; shfl src lane i = grp+4k <= 63, active.
        int iters = (deg + 3) >> 2;
        for (int k = 0; k < iters; ++k) {
            int i = grp + 4 * k;
            float ex = __shfl(exr, i, 64);
            int   e  = __shfl(eid, i, 64);
            if (i < deg) {
                float4 mm = load_row<BF>(M4, Mbf, e, sl);
                acc.x += ex * mm.x;
                acc.y += ex * mm.y;
                acc.z += ex * mm.z;
                acc.w += ex * mm.w;
            }
        }
        acc.x += __shfl_xor(acc.x, 16, 64);  acc.x += __shfl_xor(acc.x, 32, 64);
        acc.y += __shfl_xor(acc.y, 16, 64);  acc.y += __shfl_xor(acc.y, 32, 64);
        acc.z += __shfl_xor(acc.z, 16, 64);  acc.z += __shfl_xor(acc.z, 32, 64);
        acc.w += __shfl_xor(acc.w, 16, 64);  acc.w += __shfl_xor(acc.w, 32, 64);
        if (lane < 16) {
            float4 o;
            o.x = acc.x * inv; o.y = acc.y * inv;
            o.z = acc.z * inv; o.w = acc.w * inv;
            Mv4[(size_t)n * 16 + lane] = o;
        }
    } else {
        float m = -FLT_MAX;
        for (int i = beg + lane; i < end; i += 64)
            m = fmaxf(m, sorted_score[i]);
        #pragma unroll
        for (int off = 32; off; off >>= 1)
            m = fmaxf(m, __shfl_xor(m, off, 64));
        float dsum = 0.f;
        for (int i = beg + grp; i < end; i += 4) {
            int e = sorted_eid[i];
            float ex = expf(sorted_score[i] - m);
            if (sl == 0) dsum += ex;
            float4 mm = load_row<BF>(M4, Mbf, e, sl);
            acc.x += ex * mm.x;
            acc.y += ex * mm.y;
            acc.z += ex * mm.z;
            acc.w += ex * mm.w;
        }
        dsum += __shfl_xor(dsum, 16, 64);
        dsum += __shfl_xor(dsum, 32, 64);
        float dtot = __shfl(dsum, 0, 64);
        float inv = dtot > 0.f ? 1.0f / dtot : 0.0f;
        for (int i = beg + lane; i < end; i += 64) {
            alpha[sorted_eid[i]] = expf(sorted_score[i] - m) * inv;
        }
        acc.x += __shfl_xor(acc.x, 16, 64);  acc.x += __shfl_xor(acc.x, 32, 64);
        acc.y += __shfl_xor(acc.y, 16, 64);  acc.y += __shfl_xor(acc.y, 32, 64);
        acc.z += __shfl_xor(acc.z, 16, 64);  acc.z += __shfl_xor(acc.z, 32, 64);
        acc.w += __shfl_xor(acc.w, 16, 64);  acc.w += __shfl_xor(acc.w, 32, 64);
        if (lane < 16) {
            float4 o;
            o.x = acc.x * inv; o.y = acc.y * inv;
            o.z = acc.z * inv; o.w = acc.w * inv;
            Mv4[(size_t)n * 16 + lane] = o;
        }
    }
}

// ---------------------------------------------------------------------------
// K5: 16 lanes/edge. out = Mv[src] - alpha[rev] * M[rev]. Per-lane
// same-address scalar loads (HW broadcast). Nontemporal store so the 205MB
// out-stream doesn't evict the gathered M rows from L3.
template<bool BF>
__global__ void k_out(const float4* __restrict__ M4,
                      const ushort4* __restrict__ Mbf,
                      const float4* __restrict__ Mv4,
                      const float* __restrict__ alpha,
                      const int* __restrict__ src,
                      const int* __restrict__ rev,
                      f32x4* __restrict__ out4,
                      int E) {
    long long gid = (long long)blockIdx.x * blockDim.x + threadIdx.x;
    int e  = (int)(gid >> 4);
    int sl = (int)(gid & 15);
    if (e >= E) return;
    int s    = src[e];
    int r    = rev[e];
    float al = alpha[r];
    float4 mv = Mv4[(size_t)s * 16 + sl];
    float4 mr = load_row<BF>(M4, Mbf, r, sl);
    f32x4 o;
    o.x = mv.x - al * mr.x;
    o.y = mv.y - al * mr.y;
    o.z = mv.z - al * mr.z;
    o.w = mv.w - al * mr.w;
    __builtin_nontemporal_store(o, &out4[(size_t)e * 16 + sl]);
}

// ---------------------------------------------------------------------------
extern "C" void kernel_launch(void* const* d_in, const int* in_sizes, int n_in,
                              void* d_out, int out_size, void* d_ws, size_t ws_size,
                              hipStream_t stream) {
    const float* M  = (const float*)d_in[0];
    const float* a  = (const float*)d_in[1];
    const int* eidx = (const int*)d_in[2];   // [2, E] flat: src row, dest row
    const int* rev  = (const int*)d_in[3];
    const int N = 50000;
    const int E = in_sizes[3];

    const int* src  = eidx;
    const int* dest = eidx + E;

    // Workspace: Mv[N*64] f32 | Mbf[E*64] bf16 | sorted_score[E] | alpha[E] |
    //            sorted_eid[E] | counts[N]+total[4] | offsets[N] | cursor[N]
    size_t need = (size_t)N * 64 * 4 + (size_t)E * 64 * 2 + (size_t)E * 4 * 3
                + (size_t)(N + 4) * 4 + (size_t)N * 4 * 2;
    bool useBF = ws_size >= need;

    char* ws = (char*)d_ws;
    float*   Mv  = (float*)ws;   ws += (size_t)N * 64 * 4;
    ushort4* Mbf = (ushort4*)ws; if (useBF) ws += (size_t)E * 64 * 2;
    float* sorted_score = (float*)ws; ws += (size_t)E * 4;
    float* alpha        = (float*)ws; ws += (size_t)E * 4;
    int*   sorted_eid   = (int*)ws;   ws += (size_t)E * 4;
    int*   counts       = (int*)ws;   ws += (size_t)(N + 4) * 4;  // +total
    int*   offsets      = (int*)ws;   ws += (size_t)N * 4;
    int*   cursor       = (int*)ws;   ws += (size_t)N * 4;
    int*   total        = counts + N;

    long long tE16 = (long long)E * 16;
    int blocksE16 = (int)((tE16 + THREADS - 1) / THREADS);
    int blocksE   = (E + THREADS - 1) / THREADS;
    int blocksN   = (N + THREADS - 1) / THREADS;
    int blocksN64 = (int)(((long long)N * 64 + THREADS - 1) / THREADS);
    int n4        = (N + 4) / 4;               // counts + total
    int blocksZ   = (n4 + THREADS - 1) / THREADS;

    k_zero<<<blocksZ, THREADS, 0, stream>>>((int4*)counts, n4);
    k_hist<<<blocksE, THREADS, 0, stream>>>(dest, counts, E);
    k_alloc<<<blocksN, THREADS, 0, stream>>>(counts, total, offsets, cursor, N);
    if (useBF) {
        k_score_fill<true><<<blocksE16, THREADS, 0, stream>>>(
            (const float4*)M, (const float4*)a, dest, cursor,
            sorted_eid, sorted_score, Mbf, E);
        k_aggregate<true><<<blocksN64, THREADS, 0, stream>>>(
            (const float4*)M, Mbf, sorted_score, sorted_eid, offsets, counts,
            (float4*)Mv, alpha, N);
        k_out<true><<<blocksE16, THREADS, 0, stream>>>(
            (const float4*)M, Mbf, (const float4*)Mv, alpha, src, rev,
            (f32x4*)d_out, E);
    } else {
        k_score_fill<false><<<blocksE16, THREADS, 0, stream>>>(
            (const float4*)M, (const float4*)a, dest, cursor,
            sorted_eid, sorted_score, Mbf, E);
        k_aggregate<false><<<blocksN64, THREADS, 0, stream>>>(
            (const float4*)M, Mbf, sorted_score, sorted_eid, offsets, counts,
            (float4*)Mv, alpha, N);
        k_out<false><<<blocksE16, THREADS, 0, stream>>>(
            (const float4*)M, Mbf, (const float4*)Mv, alpha, src, rev,
            (f32x4*)d_out, E);
    }
}